// Round 11
// baseline (673.808 us; speedup 1.0000x reference)
//
#include <hip/hip_runtime.h>
#include <hip/hip_bf16.h>
#include <cstdint>
#include <cstddef>

typedef __attribute__((ext_vector_type(8))) short bf16x8;
typedef __attribute__((ext_vector_type(4))) float f32x4;

#define DEVI __device__ __forceinline__

DEVI unsigned short f2bf(float f) {
  union { float f; unsigned u; } x; x.f = f;
  unsigned r = x.u + 0x7fffu + ((x.u >> 16) & 1u);
  return (unsigned short)(r >> 16);
}

DEVI float exp2fast(float x) {
#if __has_builtin(__builtin_amdgcn_exp2f)
  return __builtin_amdgcn_exp2f(x);
#else
  return exp2f(x);
#endif
}

DEVI void gload_lds16(const void* g, void* l) {
  __builtin_amdgcn_global_load_lds((const __attribute__((address_space(1))) void*)g,
                                   (__attribute__((address_space(3))) void*)l, 16, 0, 0);
}

DEVI f32x4 mfma16(bf16x8 a, bf16x8 b, f32x4 c) {
  return __builtin_amdgcn_mfma_f32_16x16x32_bf16(a, b, c, 0, 0, 0);
}

// ---------------- weight transpose fp32 (K,N) -> bf16 (N,K) ----------------
__global__ __launch_bounds__(256) void transpose_to_bf16(
    const float* __restrict__ w, unsigned short* __restrict__ wt, int K, int N) {
  __shared__ float tile[32][33];
  const int n0 = blockIdx.x * 32, k0 = blockIdx.y * 32;
  const int tx = threadIdx.x, ty = threadIdx.y;
#pragma unroll
  for (int i = 0; i < 4; i++)
    tile[ty + i * 8][tx] = w[(size_t)(k0 + ty + i * 8) * N + n0 + tx];
  __syncthreads();
#pragma unroll
  for (int i = 0; i < 4; i++)
    wt[(size_t)(n0 + ty + i * 8) * K + k0 + tx] = f2bf(tile[tx][ty + i * 8]);
}

// ---------------- bf16 per-head transpose (BH,T,HS) -> (BH,HS,T) ----------------
__global__ __launch_bounds__(256) void transpose_v(
    const unsigned short* __restrict__ in, unsigned short* __restrict__ out) {
  __shared__ unsigned short tile[32][33];
  const int bh = blockIdx.z;
  const unsigned short* inp = in + (size_t)bh * 2048 * 128;
  unsigned short* op = out + (size_t)bh * 2048 * 128;
  const int t0 = blockIdx.x * 32, d0 = blockIdx.y * 32;
  const int tx = threadIdx.x, ty = threadIdx.y;
#pragma unroll
  for (int i = 0; i < 4; i++)
    tile[ty + i * 8][tx] = inp[(size_t)(t0 + ty + i * 8) * 128 + d0 + tx];
  __syncthreads();
#pragma unroll
  for (int i = 0; i < 4; i++)
    op[(size_t)(d0 + ty + i * 8) * 2048 + t0 + tx] = tile[tx][ty + i * 8];
}

// ---------------- LayerNorm: f32 row(2048) -> bf16 ----------------
__global__ __launch_bounds__(256) void ln_kernel(
    const float* __restrict__ x, const float* __restrict__ gw,
    const float* __restrict__ gb, unsigned short* __restrict__ out) {
  __shared__ float red[8];
  const int row = blockIdx.x, tid = threadIdx.x;
  const float* xr = x + (size_t)row * 2048;
  f32x4 a = *((const f32x4*)xr + tid * 2);
  f32x4 b = *((const f32x4*)xr + tid * 2 + 1);
  float s = a[0] + a[1] + a[2] + a[3] + b[0] + b[1] + b[2] + b[3];
#pragma unroll
  for (int m = 32; m >= 1; m >>= 1) s += __shfl_xor(s, m, 64);
  if ((tid & 63) == 0) red[tid >> 6] = s;
  __syncthreads();
  const float mu = (red[0] + red[1] + red[2] + red[3]) * (1.f / 2048.f);
  float d[8]; float ss = 0.f;
#pragma unroll
  for (int j = 0; j < 8; j++) {
    float v = ((j < 4) ? a[j] : b[j - 4]) - mu;
    d[j] = v; ss += v * v;
  }
#pragma unroll
  for (int m = 32; m >= 1; m >>= 1) ss += __shfl_xor(ss, m, 64);
  if ((tid & 63) == 0) red[4 + (tid >> 6)] = ss;
  __syncthreads();
  const float var = (red[4] + red[5] + red[6] + red[7]) * (1.f / 2048.f);
  const float rstd = rsqrtf(var + 1e-5f);
  f32x4 w0 = *((const f32x4*)gw + tid * 2), w1 = *((const f32x4*)gw + tid * 2 + 1);
  f32x4 b0 = *((const f32x4*)gb + tid * 2), b1 = *((const f32x4*)gb + tid * 2 + 1);
  union { bf16x8 v; unsigned short u[8]; } o;
#pragma unroll
  for (int j = 0; j < 8; j++) {
    float wv = (j < 4) ? w0[j] : w1[j - 4];
    float bv = (j < 4) ? b0[j] : b1[j - 4];
    o.u[j] = f2bf(d[j] * rstd * wv + bv);
  }
  *(bf16x8*)(out + (size_t)row * 2048 + tid * 8) = o.v;
}

// =====================================================================
// Shared epilogue: C[row,col] with row = m0+(2jj+wm)*16+g*4+r, col = n0+(4n+wn)*16+i
// EPI 0: QKV scatter to q/k/v head layout bf16; EPI 1: GELU -> bf16; EPI 2: +res -> f32
template <int EPI>
DEVI void epilogue_store(float v, int row, int col, int Nn,
                         const float* __restrict__ res, float* __restrict__ outf,
                         unsigned short* __restrict__ outb, unsigned short* __restrict__ oq,
                         unsigned short* __restrict__ ok, unsigned short* __restrict__ ov) {
  if constexpr (EPI == 0) {
    const int which = col >> 11, cc = col & 2047;
    const int hh = cc >> 7, hs = cc & 127;
    const int bb = row >> 11, tt = row & 2047;
    const size_t bh = (size_t)(bb * 16 + hh);
    const unsigned short bits = f2bf(v);
    if (which == 0) oq[(bh * 2048 + tt) * 128 + hs] = bits;
    else if (which == 1) ok[(bh * 2048 + tt) * 128 + hs] = bits;
    else ov[(bh * 2048 + tt) * 128 + hs] = bits;
  } else if constexpr (EPI == 1) {
    const float ge = 0.5f * v * (1.0f + erff(v * 0.70710678118654752f));
    outb[(size_t)row * Nn + col] = f2bf(ge);
  } else {
    outf[(size_t)row * Nn + col] = v + res[(size_t)row * Nn + col];
  }
}

#define BAR() do { __builtin_amdgcn_s_barrier(); __builtin_amdgcn_sched_barrier(0); } while (0)
#define LGKM0() do { asm volatile("s_waitcnt lgkmcnt(0)" ::: "memory"); __builtin_amdgcn_sched_barrier(0); } while (0)

// ---------------- 256x256 m201-style 4-phase deep-pipelined GEMM (FC) ----------------
// v12: faithful port of the verified 8-phase/2-K-tile template (guide §5.5
// T3+T4+T5). Per phase: [ds-reads; stage 1 half-tile; BAR1; lgkm0; 16 MFMA
// (setprio); BAR2]. ONE counted vmcnt(6) per K-tile at ph3 (3 half-tiles =
// 6 loads stay in flight across phases). Half-tile ring (B0=b_lo cols,
// A0=a_lo rows, B1=b_hi, A1=a_hi):
//   ph0(t): read b_lo,a_lo(t);  stage A1(t+1)->nxt;  q00
//   ph1(t): read b_hi(t);       stage B0(t+2)->cur;  q01
//   ph2(t): read a_hi(t);       stage A0(t+2)->cur;  q10
//   ph3(t):                     stage B1(t+2)->cur; vmcnt(6); q11
// FIFO (induction-verified): entering tile t, in-flight = [B0,A0,B1](t+1);
// ph3(t)'s vmcnt(6) drains all of tile t+1's halves >=2 barriers before
// their reads. WAR: every region's reads retire at lgkm0 before that
// phase's BAR2; its overwrite is >=1 barrier later (all 4 regions checked).
// Tails: t=NT-2 ph3 vmcnt(0); t=NT-1 no stages/waits.
template <int EPI>
__global__ __launch_bounds__(512, 2) void gemm256(
    const unsigned short* __restrict__ A, const unsigned short* __restrict__ Bt,
    const float* __restrict__ bias, const float* __restrict__ res,
    float* __restrict__ outf, unsigned short* __restrict__ outb,
    unsigned short* __restrict__ oq, unsigned short* __restrict__ ok,
    unsigned short* __restrict__ ov, int Nn, int Kk, int nbn) {
  __shared__ unsigned short As[2][256 * 64];
  __shared__ unsigned short Bs[2][256 * 64];
  const int tid = threadIdx.x;
  const int lane = tid & 63, wid = tid >> 6;
  const int i = lane & 15, g = lane >> 4;
  const int wm = wid >> 2, wn = wid & 3;
  const int nwg = gridDim.x;
  const int sid = (blockIdx.x & 7) * (nwg >> 3) + (blockIdx.x >> 3);
  const int m0 = (sid / nbn) * 256, n0 = (sid % nbn) * 256;

  auto stageA = [&](int bf, int kt, int h) {
#pragma unroll
    for (int c = 0; c < 2; c++) {
      const int cb = h * 1024 + c * 512 + wid * 64;
      const int ci = cb + lane;
      const int row = ci >> 3;
      const int kc = (ci & 7) ^ (row & 7);
      gload_lds16(A + (size_t)(m0 + row) * Kk + kt + kc * 8, &As[bf][(size_t)cb * 8]);
    }
  };
  auto stageB = [&](int bf, int kt, int h) {
#pragma unroll
    for (int c = 0; c < 2; c++) {
      const int cb = h * 1024 + c * 512 + wid * 64;
      const int ci = cb + lane;
      const int row = ci >> 3;
      const int kc = (ci & 7) ^ (row & 7);
      gload_lds16(Bt + (size_t)(n0 + row) * Kk + kt + kc * 8, &Bs[bf][(size_t)cb * 8]);
    }
  };
  auto ldA = [&](int bf, int jj, int ks) -> bf16x8 {
    const int row = (2 * jj + wm) * 16 + i;
    return *(const bf16x8*)((const char*)&As[bf][0] + row * 128 + ((((ks << 2) + g) ^ (i & 7)) << 4));
  };
  auto ldB = [&](int bf, int n, int ks) -> bf16x8 {
    const int row = (4 * n + wn) * 16 + i;
    return *(const bf16x8*)((const char*)&Bs[bf][0] + row * 128 + ((((ks << 2) + g) ^ (i & 7)) << 4));
  };

  f32x4 acc[8][4] = {};
  const int NT = Kk >> 6;

  // Prologue (template): stage tile0 (4 halves); vmcnt(4); stage tile1's
  // first 3 halves; vmcnt(6) -> tile0 fully drained, [B0,A0,B1](1) in flight.
  stageB(0, 0, 0);
  stageA(0, 0, 0);
  stageB(0, 0, 1);
  stageA(0, 0, 1);
  if (NT > 1) {
    asm volatile("s_waitcnt vmcnt(4)" ::: "memory");
    stageB(1, 64, 0);
    stageA(1, 64, 0);
    stageB(1, 64, 1);
    asm volatile("s_waitcnt vmcnt(6)" ::: "memory");
  } else {
    asm volatile("s_waitcnt vmcnt(0)" ::: "memory");
  }
  BAR();

  bf16x8 a_lo[4][2], a_hi[4][2], b_lo[2][2], b_hi[2][2];
  for (int t = 0; t < NT; ++t) {
    const int cur = t & 1, nxt = cur ^ 1;
    const int kt1 = (t + 1) << 6, kt2 = (t + 2) << 6;
    const bool h1 = (t + 1) < NT, h2 = (t + 2) < NT;
    // ---- ph0: read b_lo,a_lo(t); stage A1(t+1); MFMA q00
#pragma unroll
    for (int n = 0; n < 2; n++) { b_lo[n][0] = ldB(cur, n, 0); b_lo[n][1] = ldB(cur, n, 1); }
#pragma unroll
    for (int jj = 0; jj < 4; jj++) { a_lo[jj][0] = ldA(cur, jj, 0); a_lo[jj][1] = ldA(cur, jj, 1); }
    if (h1) stageA(nxt, kt1, 1);
    BAR();
    LGKM0();
    __builtin_amdgcn_s_setprio(1);
#pragma unroll
    for (int jj = 0; jj < 4; jj++)
#pragma unroll
      for (int n = 0; n < 2; n++) {
        acc[jj][n] = mfma16(a_lo[jj][0], b_lo[n][0], acc[jj][n]);
        acc[jj][n] = mfma16(a_lo[jj][1], b_lo[n][1], acc[jj][n]);
      }
    __builtin_amdgcn_s_setprio(0);
    BAR();
    // ---- ph1: read b_hi(t); stage B0(t+2)->cur; MFMA q01
#pragma unroll
    for (int n = 0; n < 2; n++) { b_hi[n][0] = ldB(cur, 2 + n, 0); b_hi[n][1] = ldB(cur, 2 + n, 1); }
    if (h2) stageB(cur, kt2, 0);
    BAR();
    LGKM0();
    __builtin_amdgcn_s_setprio(1);
#pragma unroll
    for (int jj = 0; jj < 4; jj++)
#pragma unroll
      for (int n = 0; n < 2; n++) {
        acc[jj][2 + n] = mfma16(a_lo[jj][0], b_hi[n][0], acc[jj][2 + n]);
        acc[jj][2 + n] = mfma16(a_lo[jj][1], b_hi[n][1], acc[jj][2 + n]);
      }
    __builtin_amdgcn_s_setprio(0);
    BAR();
    // ---- ph2: read a_hi(t); stage A0(t+2)->cur; MFMA q10
#pragma unroll
    for (int jj = 0; jj < 4; jj++) { a_hi[jj][0] = ldA(cur, 4 + jj, 0); a_hi[jj][1] = ldA(cur, 4 + jj, 1); }
    if (h2) stageA(cur, kt2, 0);
    BAR();
    LGKM0();
    __builtin_amdgcn_s_setprio(1);
#pragma unroll
    for (int jj = 0; jj < 4; jj++)
#pragma unroll
      for (int n = 0; n < 2; n++) {
        acc[4 + jj][n] = mfma16(a_hi[jj][0], b_lo[n][0], acc[4 + jj][n]);
        acc[4 + jj][n] = mfma16(a_hi[jj][1], b_lo[n][1], acc[4 + jj][n]);
      }
    __builtin_amdgcn_s_setprio(0);
    BAR();
    // ---- ph3: stage B1(t+2)->cur; vmcnt(6); MFMA q11
    if (h2) {
      stageB(cur, kt2, 1);
      asm volatile("s_waitcnt vmcnt(6)" ::: "memory");  // drains all 4 halves of t+1
    } else if (h1) {
      asm volatile("s_waitcnt vmcnt(0)" ::: "memory");  // tail: drain t+1 fully
    }
    BAR();
    __builtin_amdgcn_s_setprio(1);
#pragma unroll
    for (int jj = 0; jj < 4; jj++)
#pragma unroll
      for (int n = 0; n < 2; n++) {
        acc[4 + jj][2 + n] = mfma16(a_hi[jj][0], b_hi[n][0], acc[4 + jj][2 + n]);
        acc[4 + jj][2 + n] = mfma16(a_hi[jj][1], b_hi[n][1], acc[4 + jj][2 + n]);
      }
    __builtin_amdgcn_s_setprio(0);
    BAR();
  }

#pragma unroll
  for (int jj = 0; jj < 8; jj++)
#pragma unroll
    for (int n = 0; n < 4; n++) {
      const int col = n0 + (4 * n + wn) * 16 + i;
      const float bv = bias[col];
#pragma unroll
      for (int r = 0; r < 4; r++) {
        const int row = m0 + (2 * jj + wm) * 16 + g * 4 + r;
        epilogue_store<EPI>(acc[jj][n][r] + bv, row, col, Nn, res, outf, outb, oq, ok, ov);
      }
    }
}

// ---------------- 128x256 2-phase/K-tile GEMM (QKV / proj / FC2) ----------------
// v12 = v5 verbatim (known-good).
template <int EPI>
__global__ __launch_bounds__(512, 2) void gemm128(
    const unsigned short* __restrict__ A, const unsigned short* __restrict__ Bt,
    const float* __restrict__ bias, const float* __restrict__ res,
    float* __restrict__ outf, unsigned short* __restrict__ outb,
    unsigned short* __restrict__ oq, unsigned short* __restrict__ ok,
    unsigned short* __restrict__ ov, int Nn, int Kk, int nbn) {
  __shared__ unsigned short As[2][128 * 64];   // 32 KiB
  __shared__ unsigned short Bs[2][256 * 64];   // 64 KiB
  const int tid = threadIdx.x;
  const int lane = tid & 63, wid = tid >> 6;
  const int i = lane & 15, g = lane >> 4;
  const int wm = wid >> 2, wn = wid & 3;
  const int nwg = gridDim.x;
  const int sid = (blockIdx.x & 7) * (nwg >> 3) + (blockIdx.x >> 3);
  const int m0 = (sid / nbn) * 128, n0 = (sid % nbn) * 256;

  auto stageA = [&](int bf, int kt) {
#pragma unroll
    for (int c = 0; c < 2; c++) {
      const int cb = c * 512 + wid * 64;
      const int ci = cb + lane;
      const int row = ci >> 3;
      const int kc = (ci & 7) ^ (row & 7);
      gload_lds16(A + (size_t)(m0 + row) * Kk + kt + kc * 8, &As[bf][(size_t)cb * 8]);
    }
  };
  auto stageB = [&](int bf, int kt, int h) {
#pragma unroll
    for (int c = 0; c < 2; c++) {
      const int cb = h * 1024 + c * 512 + wid * 64;
      const int ci = cb + lane;
      const int row = ci >> 3;
      const int kc = (ci & 7) ^ (row & 7);
      gload_lds16(Bt + (size_t)(n0 + row) * Kk + kt + kc * 8, &Bs[bf][(size_t)cb * 8]);
    }
  };
  auto ldA = [&](int bf, int jj, int ks) -> bf16x8 {
    const int row = (2 * jj + wm) * 16 + i;
    return *(const bf16x8*)((const char*)&As[bf][0] + row * 128 + ((((ks << 2) + g) ^ (i & 7)) << 4));
  };
  auto ldB = [&](int bf, int n, int ks) -> bf16x8 {
    const int row = (4 * n + wn) * 16 + i;
    return *(const bf16x8*)((const char*)&Bs[bf][0] + row * 128 + ((((ks << 2) + g) ^ (i & 7)) << 4));
  };

  f32x4 acc[4][4] = {};
  const int NT = Kk >> 6;

  stageA(0, 0);
  stageB(0, 0, 0);
  stageB(0, 0, 1);
  asm volatile("s_waitcnt vmcnt(2)" ::: "memory");
  __builtin_amdgcn_s_barrier();
  __builtin_amdgcn_sched_barrier(0);

  bf16x8 af[4][2], b_lo[2][2], b_hi[2][2];
  for (int t = 0; t < NT; ++t) {
    const int cur = t & 1, nxt = cur ^ 1;
    const int ktn = (t + 1) << 6;
    const bool hn = (t + 1) < NT;
    // ---- PH0: read b_lo,af(cur); stage A+B-h0(nxt); drain B-h1(cur)
#pragma unroll
    for (int n = 0; n < 2; n++) { b_lo[n][0] = ldB(cur, n, 0); b_lo[n][1] = ldB(cur, n, 1); }
#pragma unroll
    for (int jj = 0; jj < 4; jj++) { af[jj][0] = ldA(cur, jj, 0); af[jj][1] = ldA(cur, jj, 1); }
    if (hn) { stageA(nxt, ktn); stageB(nxt, ktn, 0); }
    if (hn) asm volatile("s_waitcnt vmcnt(4)" ::: "memory");
    else    asm volatile("s_waitcnt vmcnt(0)" ::: "memory");
    __builtin_amdgcn_s_barrier();
    __builtin_amdgcn_sched_barrier(0);
    __builtin_amdgcn_s_setprio(1);
#pragma unroll
    for (int jj = 0; jj < 4; jj++)
#pragma unroll
      for (int n = 0; n < 2; n++) {
        acc[jj][n] = mfma16(af[jj][0], b_lo[n][0], acc[jj][n]);
        acc[jj][n] = mfma16(af[jj][1], b_lo[n][1], acc[jj][n]);
      }
    __builtin_amdgcn_s_setprio(0);
    // ---- PH1: read b_hi(cur); stage B-h1(nxt); drain A,B-h0(nxt)
#pragma unroll
    for (int n = 0; n < 2; n++) { b_hi[n][0] = ldB(cur, 2 + n, 0); b_hi[n][1] = ldB(cur, 2 + n, 1); }
    if (hn) stageB(nxt, ktn, 1);
    if (hn) asm volatile("s_waitcnt vmcnt(2)" ::: "memory");
    __builtin_amdgcn_s_barrier();
    __builtin_amdgcn_sched_barrier(0);
    __builtin_amdgcn_s_setprio(1);
#pragma unroll
    for (int jj = 0; jj < 4; jj++)
#pragma unroll
      for (int n = 0; n < 2; n++) {
        acc[jj][2 + n] = mfma16(af[jj][0], b_hi[n][0], acc[jj][2 + n]);
        acc[jj][2 + n] = mfma16(af[jj][1], b_hi[n][1], acc[jj][2 + n]);
      }
    __builtin_amdgcn_s_setprio(0);
  }

#pragma unroll
  for (int jj = 0; jj < 4; jj++)
#pragma unroll
    for (int n = 0; n < 4; n++) {
      const int col = n0 + (4 * n + wn) * 16 + i;
      const float bv = bias[col];
#pragma unroll
      for (int r = 0; r < 4; r++) {
        const int row = m0 + (2 * jj + wm) * 16 + g * 4 + r;
        epilogue_store<EPI>(acc[jj][n][r] + bv, row, col, Nn, res, outf, outb, oq, ok, ov);
      }
    }
}

// ---------------- causal flash attention (paired q-tiles, swapped QK^T) ----------------
// v12 = known-good single-buffered version.
__global__ __launch_bounds__(256) void attn_kernel(
    const unsigned short* __restrict__ q, const unsigned short* __restrict__ k,
    const unsigned short* __restrict__ vt, unsigned short* __restrict__ y) {
  __shared__ unsigned short Ks[64 * 128];   // swizzled [kv][hs]
  __shared__ unsigned short Vs[128 * 64];   // swizzled [d][kv]
  __shared__ unsigned short Ps[4][16 * 64]; // per-wave swizzled [q=i][kv]
  const int tid = threadIdx.x, lane = tid & 63, w = tid >> 6;
  const int i = lane & 15, g = lane >> 4;
  const int p = blockIdx.x, bh = blockIdx.y;
  const int q0A = p * 64, q0B = (31 - p) * 64;
  const int tB = 31 - p;
  const size_t hb = (size_t)bh * (2048 * 128);
  const float sc2 = 0.08838834764831845f * 1.44269504088896341f;

  bf16x8 qfA[4], qfB[4];
  {
    const int qra = q0A + w * 16 + i, qrb = q0B + w * 16 + i;
#pragma unroll
    for (int kc = 0; kc < 4; kc++) {
      qfA[kc] = *(const bf16x8*)(q + hb + (size_t)qra * 128 + kc * 32 + g * 8);
      qfB[kc] = *(const bf16x8*)(q + hb + (size_t)qrb * 128 + kc * 32 + g * 8);
    }
  }
  f32x4 oA[8] = {}, oB[8] = {};
  float mA = -__builtin_inff(), lA = 0.f, mB = -__builtin_inff(), lB = 0.f;

  auto proc = [&](const bf16x8 (&qf)[4], f32x4 (&oacc)[8], float& mrun, float& lrun,
                  bool diag) {
    f32x4 st[4];
#pragma unroll
    for (int ct = 0; ct < 4; ct++) {
      f32x4 a = {};
      const int kvr = ct * 16 + i;
#pragma unroll
      for (int kc = 0; kc < 4; kc++) {
        bf16x8 kf = *(const bf16x8*)((char*)Ks + kvr * 256 + (((kc * 4 + g) ^ (i & 7)) << 4));
        a = mfma16(kf, qf[kc], a);
      }
      st[ct] = a;
    }
    float tm = -__builtin_inff();
    const int ql = w * 16 + i;
#pragma unroll
    for (int ct = 0; ct < 4; ct++)
#pragma unroll
      for (int r = 0; r < 4; r++) {
        float v = st[ct][r] * sc2;
        if (diag) {
          const int kvl = ct * 16 + g * 4 + r;
          if (kvl > ql) v = -__builtin_inff();
        }
        st[ct][r] = v;
        tm = fmaxf(tm, v);
      }
    tm = fmaxf(tm, __shfl_xor(tm, 16, 64));
    tm = fmaxf(tm, __shfl_xor(tm, 32, 64));
    if (!__all(tm - mrun <= 8.f)) {
      const float mnew = fmaxf(mrun, tm);
      const float al = exp2fast(mrun - mnew);
      float ar[4];
#pragma unroll
      for (int r = 0; r < 4; r++) ar[r] = __shfl(al, g * 4 + r, 64);
#pragma unroll
      for (int dt = 0; dt < 8; dt++)
#pragma unroll
        for (int r = 0; r < 4; r++) oacc[dt][r] *= ar[r];
      lrun *= al;
      mrun = mnew;
    }
    float ps = 0.f;
#pragma unroll
    for (int ct = 0; ct < 4; ct++)
#pragma unroll
      for (int r = 0; r < 4; r++) {
        const float pv = exp2fast(st[ct][r] - mrun);
        st[ct][r] = pv;
        ps += pv;
      }
    ps += __shfl_xor(ps, 16, 64);
    ps += __shfl_xor(ps, 32, 64);
    lrun += ps;
#pragma unroll
    for (int ct = 0; ct < 4; ct++) {
      unsigned w0, w1;
      asm("v_cvt_pk_bf16_f32 %0, %1, %2" : "=v"(w0) : "v"(st[ct][0]), "v"(st[ct][1]));
      asm("v_cvt_pk_bf16_f32 %0, %1, %2" : "=v"(w1) : "v"(st[ct][2]), "v"(st[ct][3]));
      char* pb = (char*)&Ps[w][0] + i * 128 +
                 ((((2 * ct + (g >> 1)) ^ (i & 7)) << 4) + (g & 1) * 8);
      *(uint2*)pb = make_uint2(w0, w1);
    }
    bf16x8 pf[2];
#pragma unroll
    for (int kvc = 0; kvc < 2; kvc++)
      pf[kvc] = *(const bf16x8*)((char*)&Ps[w][0] + i * 128 + (((kvc * 4 + g) ^ (i & 7)) << 4));
#pragma unroll
    for (int dt = 0; dt < 8; dt++) {
      const int dr = dt * 16 + i;
#pragma unroll
      for (int kvc = 0; kvc < 2; kvc++) {
        bf16x8 vf = *(const bf16x8*)((char*)Vs + dr * 128 + (((kvc * 4 + g) ^ (dr & 7)) << 4));
        oacc[dt] = mfma16(pf[kvc], vf, oacc[dt]);
      }
    }
  };

  for (int t = 0; t <= tB; ++t) {
    const int j0 = t * 64;
    __syncthreads();
#pragma unroll
    for (int it = 0; it < 4; it++) {
      const int ci = it * 256 + tid;
      const int kv = ci >> 4, ccl = ci & 15;
      gload_lds16(k + hb + (size_t)(j0 + kv) * 128 + ((ccl ^ (kv & 7)) << 3),
                  (char*)Ks + (size_t)(it * 256 + w * 64) * 16);
      const int dd = ci >> 3, c2l = ci & 7;
      gload_lds16(vt + hb + (size_t)dd * 2048 + j0 + ((c2l ^ (dd & 7)) << 3),
                  (char*)Vs + (size_t)(it * 256 + w * 64) * 16);
    }
    __syncthreads();
    if (t <= p) proc(qfA, oA, mA, lA, t == p);
    proc(qfB, oB, mB, lB, t == tB);
  }

  const int bb = bh >> 4, hh = bh & 15;
  auto finish = [&](const f32x4 (&oacc)[8], float lrun, int q0s) {
    const float inv_i = 1.f / lrun;
    float ir[4];
#pragma unroll
    for (int r = 0; r < 4; r++) ir[r] = __shfl(inv_i, g * 4 + r, 64);
#pragma unroll
    for (int r = 0; r < 4; r++) {
      const int row = q0s + w * 16 + g * 4 + r;
#pragma unroll
      for (int dt = 0; dt < 8; dt++) {
        const int d = dt * 16 + i;
        y[((size_t)(bb * 2048 + row)) * 2048 + hh * 128 + d] = f2bf(oacc[dt][r] * ir[r]);
      }
    }
  };
  finish(oA, lA, q0A);
  finish(oB, lB, q0B);
}

// ---------------- launcher ----------------
extern "C" void kernel_launch(void* const* d_in, const int* in_sizes, int n_in,
                              void* d_out, int out_size, void* d_ws, size_t ws_size,
                              hipStream_t stream) {
  const float* x      = (const float*)d_in[0];
  const float* ln1_w  = (const float*)d_in[1];
  const float* ln1_b  = (const float*)d_in[2];
  const float* w_qkv  = (const float*)d_in[3];
  const float* b_qkv  = (const float*)d_in[4];
  const float* w_proj = (const float*)d_in[5];
  const float* b_proj = (const float*)d_in[6];
  const float* ln2_w  = (const float*)d_in[7];
  const float* ln2_b  = (const float*)d_in[8];
  const float* w_fc   = (const float*)d_in[9];
  const float* b_fc   = (const float*)d_in[10];
  const float* w_fc2  = (const float*)d_in[11];
  const float* b_fc2  = (const float*)d_in[12];

  char* ws = (char*)d_ws;
  unsigned short* wt_qkv  = (unsigned short*)(ws + 0);          // 25165824 B
  unsigned short* wt_proj = (unsigned short*)(ws + 25165824);   // 8388608
  unsigned short* qb      = (unsigned short*)(ws + 33554432);   // 16777216
  unsigned short* kb      = (unsigned short*)(ws + 50331648);   // 16777216
  unsigned short* wt_fc   = (unsigned short*)(ws + 67108864);   // 33554432
  unsigned short* wt_fc2  = (unsigned short*)(ws + 100663296);  // 33554432
  unsigned short* hb      = (unsigned short*)(ws + 134217728);  // 16777216 (h1/h2)
  unsigned short* vtb     = (unsigned short*)(ws + 150994944);  // 16777216
  unsigned short* yb      = (unsigned short*)(ws + 167772160);  // 16777216 (vb then y)
  float*          x1      = (float*)(ws + 184549376);           // 33554432 (ends 218103808)
  unsigned short* hfc     = (unsigned short*)(ws + 0);          // 67108864, aliases dead wt_qkv/wt_proj/qb/kb
  float* outp = (float*)d_out;

  dim3 tb(32, 8);
  transpose_to_bf16<<<dim3(6144 / 32, 2048 / 32), tb, 0, stream>>>(w_qkv, wt_qkv, 2048, 6144);
  transpose_to_bf16<<<dim3(2048 / 32, 2048 / 32), tb, 0, stream>>>(w_proj, wt_proj, 2048, 2048);
  transpose_to_bf16<<<dim3(8192 / 32, 2048 / 32), tb, 0, stream>>>(w_fc, wt_fc, 2048, 8192);
  transpose_to_bf16<<<dim3(2048 / 32, 8192 / 32), tb, 0, stream>>>(w_fc2, wt_fc2, 8192, 2048);

  ln_kernel<<<4096, 256, 0, stream>>>(x, ln1_w, ln1_b, hb);

  // qkv: 128x256 tiles -> 32x24 = 768 blocks (3 clean rounds)
  gemm128<0><<<768, 512, 0, stream>>>(
      hb, wt_qkv, b_qkv, nullptr, nullptr, nullptr, qb, kb, yb, 6144, 2048, 24);
  transpose_v<<<dim3(2048 / 32, 128 / 32, 32), tb, 0, stream>>>(yb, vtb);

  // paired causal q-tiles: 16 pairs x 32 bh = 512 blocks, uniform work
  attn_kernel<<<dim3(16, 32), 256, 0, stream>>>(qb, kb, vtb, yb);

  // proj + residual -> x1 (f32): 32x8 = 256 blocks (1 clean round)
  gemm128<2><<<256, 512, 0, stream>>>(
      yb, wt_proj, b_proj, x, x1, nullptr, nullptr, nullptr, nullptr, 2048, 2048, 8);

  ln_kernel<<<4096, 256, 0, stream>>>(x1, ln2_w, ln2_b, hb);

  // fc + GELU -> hfc (bf16): 256x256 tiles, 512 blocks (2 clean rounds)
  gemm256<1><<<512, 512, 0, stream>>>(
      hb, wt_fc, b_fc, nullptr, nullptr, hfc, nullptr, nullptr, nullptr, 8192, 2048, 32);

  // fc2 + residual -> out (f32): 32x8 = 256 blocks (1 clean round)
  gemm128<2><<<256, 512, 0, stream>>>(
      hfc, wt_fc2, b_fc2, x1, outp, nullptr, nullptr, nullptr, nullptr, 2048, 8192, 8);
}

// Round 12
// 656.360 us; speedup vs baseline: 1.0266x; 1.0266x over previous
//
#include <hip/hip_runtime.h>
#include <hip/hip_bf16.h>
#include <cstdint>
#include <cstddef>

typedef __attribute__((ext_vector_type(8))) short bf16x8;
typedef __attribute__((ext_vector_type(4))) float f32x4;

#define DEVI __device__ __forceinline__

DEVI unsigned short f2bf(float f) {
  union { float f; unsigned u; } x; x.f = f;
  unsigned r = x.u + 0x7fffu + ((x.u >> 16) & 1u);
  return (unsigned short)(r >> 16);
}

DEVI float exp2fast(float x) {
#if __has_builtin(__builtin_amdgcn_exp2f)
  return __builtin_amdgcn_exp2f(x);
#else
  return exp2f(x);
#endif
}

DEVI void gload_lds16(const void* g, void* l) {
  __builtin_amdgcn_global_load_lds((const __attribute__((address_space(1))) void*)g,
                                   (__attribute__((address_space(3))) void*)l, 16, 0, 0);
}

DEVI f32x4 mfma16(bf16x8 a, bf16x8 b, f32x4 c) {
  return __builtin_amdgcn_mfma_f32_16x16x32_bf16(a, b, c, 0, 0, 0);
}

// ---------------- weight transpose fp32 (K,N) -> bf16 (N,K) ----------------
// v13: 64x64 tile, conflict-free LDS [64][66], f32->bf16 at load, write phase
// emits two bf16x8 (16B) stores per thread -> each output n-row written as
// 128B contiguous chunks (old version: 64B). Reads stay wave-coalesced
// (64 consecutive n per k-row).
__global__ __launch_bounds__(256) void transpose_to_bf16(
    const float* __restrict__ w, unsigned short* __restrict__ wt, int K, int N) {
  __shared__ unsigned short tile[64][66];
  const int n0 = blockIdx.x * 64, k0 = blockIdx.y * 64;
  const int tid = threadIdx.x;
  const int nl = tid & 63, kl4 = tid >> 6;  // 4 k-rows per pass
#pragma unroll
  for (int p = 0; p < 16; p++) {
    const int kk = p * 4 + kl4;
    tile[nl][kk] = f2bf(w[(size_t)(k0 + kk) * N + n0 + nl]);
  }
  __syncthreads();
  const int nr = tid >> 2, ks = (tid & 3) * 16;
  union { bf16x8 v; unsigned short u[8]; } o0, o1;
#pragma unroll
  for (int j = 0; j < 8; j++) { o0.u[j] = tile[nr][ks + j]; o1.u[j] = tile[nr][ks + 8 + j]; }
  unsigned short* dst = wt + (size_t)(n0 + nr) * K + k0 + ks;
  *(bf16x8*)dst = o0.v;
  *(bf16x8*)(dst + 8) = o1.v;
}

// ---------------- bf16 per-head transpose (BH,T,HS) -> (BH,HS,T) ----------------
__global__ __launch_bounds__(256) void transpose_v(
    const unsigned short* __restrict__ in, unsigned short* __restrict__ out) {
  __shared__ unsigned short tile[32][33];
  const int bh = blockIdx.z;
  const unsigned short* inp = in + (size_t)bh * 2048 * 128;
  unsigned short* op = out + (size_t)bh * 2048 * 128;
  const int t0 = blockIdx.x * 32, d0 = blockIdx.y * 32;
  const int tx = threadIdx.x, ty = threadIdx.y;
#pragma unroll
  for (int i = 0; i < 4; i++)
    tile[ty + i * 8][tx] = inp[(size_t)(t0 + ty + i * 8) * 128 + d0 + tx];
  __syncthreads();
#pragma unroll
  for (int i = 0; i < 4; i++)
    op[(size_t)(d0 + ty + i * 8) * 2048 + t0 + tx] = tile[tx][ty + i * 8];
}

// ---------------- LayerNorm: f32 row(2048) -> bf16 ----------------
__global__ __launch_bounds__(256) void ln_kernel(
    const float* __restrict__ x, const float* __restrict__ gw,
    const float* __restrict__ gb, unsigned short* __restrict__ out) {
  __shared__ float red[8];
  const int row = blockIdx.x, tid = threadIdx.x;
  const float* xr = x + (size_t)row * 2048;
  f32x4 a = *((const f32x4*)xr + tid * 2);
  f32x4 b = *((const f32x4*)xr + tid * 2 + 1);
  float s = a[0] + a[1] + a[2] + a[3] + b[0] + b[1] + b[2] + b[3];
#pragma unroll
  for (int m = 32; m >= 1; m >>= 1) s += __shfl_xor(s, m, 64);
  if ((tid & 63) == 0) red[tid >> 6] = s;
  __syncthreads();
  const float mu = (red[0] + red[1] + red[2] + red[3]) * (1.f / 2048.f);
  float d[8]; float ss = 0.f;
#pragma unroll
  for (int j = 0; j < 8; j++) {
    float v = ((j < 4) ? a[j] : b[j - 4]) - mu;
    d[j] = v; ss += v * v;
  }
#pragma unroll
  for (int m = 32; m >= 1; m >>= 1) ss += __shfl_xor(ss, m, 64);
  if ((tid & 63) == 0) red[4 + (tid >> 6)] = ss;
  __syncthreads();
  const float var = (red[4] + red[5] + red[6] + red[7]) * (1.f / 2048.f);
  const float rstd = rsqrtf(var + 1e-5f);
  f32x4 w0 = *((const f32x4*)gw + tid * 2), w1 = *((const f32x4*)gw + tid * 2 + 1);
  f32x4 b0 = *((const f32x4*)gb + tid * 2), b1 = *((const f32x4*)gb + tid * 2 + 1);
  union { bf16x8 v; unsigned short u[8]; } o;
#pragma unroll
  for (int j = 0; j < 8; j++) {
    float wv = (j < 4) ? w0[j] : w1[j - 4];
    float bv = (j < 4) ? b0[j] : b1[j - 4];
    o.u[j] = f2bf(d[j] * rstd * wv + bv);
  }
  *(bf16x8*)(out + (size_t)row * 2048 + tid * 8) = o.v;
}

// =====================================================================
// Shared epilogue: C[row,col] with row = m0+(2jj+wm)*16+g*4+r, col = n0+(4n+wn)*16+i
// EPI 0: QKV scatter to q/k/v head layout bf16; EPI 1: GELU -> bf16; EPI 2: +res -> f32
template <int EPI>
DEVI void epilogue_store(float v, int row, int col, int Nn,
                         const float* __restrict__ res, float* __restrict__ outf,
                         unsigned short* __restrict__ outb, unsigned short* __restrict__ oq,
                         unsigned short* __restrict__ ok, unsigned short* __restrict__ ov) {
  if constexpr (EPI == 0) {
    const int which = col >> 11, cc = col & 2047;
    const int hh = cc >> 7, hs = cc & 127;
    const int bb = row >> 11, tt = row & 2047;
    const size_t bh = (size_t)(bb * 16 + hh);
    const unsigned short bits = f2bf(v);
    if (which == 0) oq[(bh * 2048 + tt) * 128 + hs] = bits;
    else if (which == 1) ok[(bh * 2048 + tt) * 128 + hs] = bits;
    else ov[(bh * 2048 + tt) * 128 + hs] = bits;
  } else if constexpr (EPI == 1) {
    const float ge = 0.5f * v * (1.0f + erff(v * 0.70710678118654752f));
    outb[(size_t)row * Nn + col] = f2bf(ge);
  } else {
    outf[(size_t)row * Nn + col] = v + res[(size_t)row * Nn + col];
  }
}

// ---------------- 256x256 2-phase/K-tile GEMM (used for FC) ----------------
// v13 = v5 verbatim (known-good, 167us; local optimum after 7 schedule
// variants: 4-phase=176, 8-phase=185-193, rotation/read-order=neutral,
// 1-phase=race. Barrier count 2/K-tile is the floor for 2-buffer WAR safety).
template <int EPI>
__global__ __launch_bounds__(512, 2) void gemm256(
    const unsigned short* __restrict__ A, const unsigned short* __restrict__ Bt,
    const float* __restrict__ bias, const float* __restrict__ res,
    float* __restrict__ outf, unsigned short* __restrict__ outb,
    unsigned short* __restrict__ oq, unsigned short* __restrict__ ok,
    unsigned short* __restrict__ ov, int Nn, int Kk, int nbn) {
  __shared__ unsigned short As[2][256 * 64];
  __shared__ unsigned short Bs[2][256 * 64];
  const int tid = threadIdx.x;
  const int lane = tid & 63, wid = tid >> 6;
  const int i = lane & 15, g = lane >> 4;
  const int wm = wid >> 2, wn = wid & 3;
  const int nwg = gridDim.x;
  const int sid = (blockIdx.x & 7) * (nwg >> 3) + (blockIdx.x >> 3);
  const int m0 = (sid / nbn) * 256, n0 = (sid % nbn) * 256;

  auto stageA = [&](int bf, int kt, int h) {
#pragma unroll
    for (int c = 0; c < 2; c++) {
      const int cb = h * 1024 + c * 512 + wid * 64;
      const int ci = cb + lane;
      const int row = ci >> 3;
      const int kc = (ci & 7) ^ (row & 7);
      gload_lds16(A + (size_t)(m0 + row) * Kk + kt + kc * 8, &As[bf][(size_t)cb * 8]);
    }
  };
  auto stageB = [&](int bf, int kt, int h) {
#pragma unroll
    for (int c = 0; c < 2; c++) {
      const int cb = h * 1024 + c * 512 + wid * 64;
      const int ci = cb + lane;
      const int row = ci >> 3;
      const int kc = (ci & 7) ^ (row & 7);
      gload_lds16(Bt + (size_t)(n0 + row) * Kk + kt + kc * 8, &Bs[bf][(size_t)cb * 8]);
    }
  };
  auto ldA = [&](int bf, int jj, int ks) -> bf16x8 {
    const int row = (2 * jj + wm) * 16 + i;
    return *(const bf16x8*)((const char*)&As[bf][0] + row * 128 + ((((ks << 2) + g) ^ (i & 7)) << 4));
  };
  auto ldB = [&](int bf, int n, int ks) -> bf16x8 {
    const int row = (4 * n + wn) * 16 + i;
    return *(const bf16x8*)((const char*)&Bs[bf][0] + row * 128 + ((((ks << 2) + g) ^ (i & 7)) << 4));
  };

  f32x4 acc[8][4] = {};
  const int NT = Kk >> 6;

  // prologue: stage tile 0 fully; drain h0 halves -> identical steady state
  stageA(0, 0, 0);
  stageB(0, 0, 0);
  stageB(0, 0, 1);
  stageA(0, 0, 1);
  asm volatile("s_waitcnt vmcnt(4)" ::: "memory");
  __builtin_amdgcn_s_barrier();
  __builtin_amdgcn_sched_barrier(0);

  bf16x8 a_lo[4][2], a_hi[4][2], b_lo[2][2], b_hi[2][2];
  for (int t = 0; t < NT; ++t) {
    const int cur = t & 1, nxt = cur ^ 1;
    const int ktn = (t + 1) << 6;
    const bool hn = (t + 1) < NT;
    // ---- ph0: read b_lo,a_lo(cur); stage A-h0+B-h0(nxt); 16 MFMA q00
#pragma unroll
    for (int n = 0; n < 2; n++) { b_lo[n][0] = ldB(cur, n, 0); b_lo[n][1] = ldB(cur, n, 1); }
#pragma unroll
    for (int jj = 0; jj < 4; jj++) { a_lo[jj][0] = ldA(cur, jj, 0); a_lo[jj][1] = ldA(cur, jj, 1); }
    if (hn) { stageA(nxt, ktn, 0); stageB(nxt, ktn, 0); }
    if (hn) asm volatile("s_waitcnt vmcnt(4)" ::: "memory");
    else    asm volatile("s_waitcnt vmcnt(0)" ::: "memory");
    __builtin_amdgcn_s_barrier();
    __builtin_amdgcn_sched_barrier(0);
    __builtin_amdgcn_s_setprio(1);
#pragma unroll
    for (int jj = 0; jj < 4; jj++)
#pragma unroll
      for (int n = 0; n < 2; n++) {
        acc[jj][n] = mfma16(a_lo[jj][0], b_lo[n][0], acc[jj][n]);
        acc[jj][n] = mfma16(a_lo[jj][1], b_lo[n][1], acc[jj][n]);
      }
    __builtin_amdgcn_s_setprio(0);
    // ---- ph1: read b_hi,a_hi(cur); stage B-h1+A-h1(nxt); 48 MFMA q01,q10,q11
#pragma unroll
    for (int n = 0; n < 2; n++) { b_hi[n][0] = ldB(cur, 2 + n, 0); b_hi[n][1] = ldB(cur, 2 + n, 1); }
#pragma unroll
    for (int jj = 0; jj < 4; jj++) { a_hi[jj][0] = ldA(cur, 4 + jj, 0); a_hi[jj][1] = ldA(cur, 4 + jj, 1); }
    if (hn) { stageB(nxt, ktn, 1); stageA(nxt, ktn, 1); }
    if (hn) asm volatile("s_waitcnt vmcnt(4)" ::: "memory");
    __builtin_amdgcn_s_barrier();
    __builtin_amdgcn_sched_barrier(0);
    __builtin_amdgcn_s_setprio(1);
    // q01: a_lo x b_hi (needs only b_hi reads)
#pragma unroll
    for (int jj = 0; jj < 4; jj++)
#pragma unroll
      for (int n = 0; n < 2; n++) {
        acc[jj][2 + n] = mfma16(a_lo[jj][0], b_hi[n][0], acc[jj][2 + n]);
        acc[jj][2 + n] = mfma16(a_lo[jj][1], b_hi[n][1], acc[jj][2 + n]);
      }
    // q10: a_hi x b_lo
#pragma unroll
    for (int jj = 0; jj < 4; jj++)
#pragma unroll
      for (int n = 0; n < 2; n++) {
        acc[4 + jj][n] = mfma16(a_hi[jj][0], b_lo[n][0], acc[4 + jj][n]);
        acc[4 + jj][n] = mfma16(a_hi[jj][1], b_lo[n][1], acc[4 + jj][n]);
      }
    // q11: a_hi x b_hi
#pragma unroll
    for (int jj = 0; jj < 4; jj++)
#pragma unroll
      for (int n = 0; n < 2; n++) {
        acc[4 + jj][2 + n] = mfma16(a_hi[jj][0], b_hi[n][0], acc[4 + jj][2 + n]);
        acc[4 + jj][2 + n] = mfma16(a_hi[jj][1], b_hi[n][1], acc[4 + jj][2 + n]);
      }
    __builtin_amdgcn_s_setprio(0);
  }

#pragma unroll
  for (int jj = 0; jj < 8; jj++)
#pragma unroll
    for (int n = 0; n < 4; n++) {
      const int col = n0 + (4 * n + wn) * 16 + i;
      const float bv = bias[col];
#pragma unroll
      for (int r = 0; r < 4; r++) {
        const int row = m0 + (2 * jj + wm) * 16 + g * 4 + r;
        epilogue_store<EPI>(acc[jj][n][r] + bv, row, col, Nn, res, outf, outb, oq, ok, ov);
      }
    }
}

// ---------------- 128x256 2-phase/K-tile GEMM (QKV / proj / FC2) ----------------
// v13 = v5 verbatim.
template <int EPI>
__global__ __launch_bounds__(512, 2) void gemm128(
    const unsigned short* __restrict__ A, const unsigned short* __restrict__ Bt,
    const float* __restrict__ bias, const float* __restrict__ res,
    float* __restrict__ outf, unsigned short* __restrict__ outb,
    unsigned short* __restrict__ oq, unsigned short* __restrict__ ok,
    unsigned short* __restrict__ ov, int Nn, int Kk, int nbn) {
  __shared__ unsigned short As[2][128 * 64];   // 32 KiB
  __shared__ unsigned short Bs[2][256 * 64];   // 64 KiB
  const int tid = threadIdx.x;
  const int lane = tid & 63, wid = tid >> 6;
  const int i = lane & 15, g = lane >> 4;
  const int wm = wid >> 2, wn = wid & 3;
  const int nwg = gridDim.x;
  const int sid = (blockIdx.x & 7) * (nwg >> 3) + (blockIdx.x >> 3);
  const int m0 = (sid / nbn) * 128, n0 = (sid % nbn) * 256;

  auto stageA = [&](int bf, int kt) {
#pragma unroll
    for (int c = 0; c < 2; c++) {
      const int cb = c * 512 + wid * 64;
      const int ci = cb + lane;
      const int row = ci >> 3;
      const int kc = (ci & 7) ^ (row & 7);
      gload_lds16(A + (size_t)(m0 + row) * Kk + kt + kc * 8, &As[bf][(size_t)cb * 8]);
    }
  };
  auto stageB = [&](int bf, int kt, int h) {
#pragma unroll
    for (int c = 0; c < 2; c++) {
      const int cb = h * 1024 + c * 512 + wid * 64;
      const int ci = cb + lane;
      const int row = ci >> 3;
      const int kc = (ci & 7) ^ (row & 7);
      gload_lds16(Bt + (size_t)(n0 + row) * Kk + kt + kc * 8, &Bs[bf][(size_t)cb * 8]);
    }
  };
  auto ldA = [&](int bf, int jj, int ks) -> bf16x8 {
    const int row = (2 * jj + wm) * 16 + i;
    return *(const bf16x8*)((const char*)&As[bf][0] + row * 128 + ((((ks << 2) + g) ^ (i & 7)) << 4));
  };
  auto ldB = [&](int bf, int n, int ks) -> bf16x8 {
    const int row = (4 * n + wn) * 16 + i;
    return *(const bf16x8*)((const char*)&Bs[bf][0] + row * 128 + ((((ks << 2) + g) ^ (i & 7)) << 4));
  };

  f32x4 acc[4][4] = {};
  const int NT = Kk >> 6;

  stageA(0, 0);
  stageB(0, 0, 0);
  stageB(0, 0, 1);
  asm volatile("s_waitcnt vmcnt(2)" ::: "memory");
  __builtin_amdgcn_s_barrier();
  __builtin_amdgcn_sched_barrier(0);

  bf16x8 af[4][2], b_lo[2][2], b_hi[2][2];
  for (int t = 0; t < NT; ++t) {
    const int cur = t & 1, nxt = cur ^ 1;
    const int ktn = (t + 1) << 6;
    const bool hn = (t + 1) < NT;
    // ---- PH0: read b_lo,af(cur); stage A+B-h0(nxt); drain B-h1(cur)
#pragma unroll
    for (int n = 0; n < 2; n++) { b_lo[n][0] = ldB(cur, n, 0); b_lo[n][1] = ldB(cur, n, 1); }
#pragma unroll
    for (int jj = 0; jj < 4; jj++) { af[jj][0] = ldA(cur, jj, 0); af[jj][1] = ldA(cur, jj, 1); }
    if (hn) { stageA(nxt, ktn); stageB(nxt, ktn, 0); }
    if (hn) asm volatile("s_waitcnt vmcnt(4)" ::: "memory");
    else    asm volatile("s_waitcnt vmcnt(0)" ::: "memory");
    __builtin_amdgcn_s_barrier();
    __builtin_amdgcn_sched_barrier(0);
    __builtin_amdgcn_s_setprio(1);
#pragma unroll
    for (int jj = 0; jj < 4; jj++)
#pragma unroll
      for (int n = 0; n < 2; n++) {
        acc[jj][n] = mfma16(af[jj][0], b_lo[n][0], acc[jj][n]);
        acc[jj][n] = mfma16(af[jj][1], b_lo[n][1], acc[jj][n]);
      }
    __builtin_amdgcn_s_setprio(0);
    // ---- PH1: read b_hi(cur); stage B-h1(nxt); drain A,B-h0(nxt)
#pragma unroll
    for (int n = 0; n < 2; n++) { b_hi[n][0] = ldB(cur, 2 + n, 0); b_hi[n][1] = ldB(cur, 2 + n, 1); }
    if (hn) stageB(nxt, ktn, 1);
    if (hn) asm volatile("s_waitcnt vmcnt(2)" ::: "memory");
    __builtin_amdgcn_s_barrier();
    __builtin_amdgcn_sched_barrier(0);
    __builtin_amdgcn_s_setprio(1);
#pragma unroll
    for (int jj = 0; jj < 4; jj++)
#pragma unroll
      for (int n = 0; n < 2; n++) {
        acc[jj][2 + n] = mfma16(af[jj][0], b_hi[n][0], acc[jj][2 + n]);
        acc[jj][2 + n] = mfma16(af[jj][1], b_hi[n][1], acc[jj][2 + n]);
      }
    __builtin_amdgcn_s_setprio(0);
  }

#pragma unroll
  for (int jj = 0; jj < 4; jj++)
#pragma unroll
    for (int n = 0; n < 4; n++) {
      const int col = n0 + (4 * n + wn) * 16 + i;
      const float bv = bias[col];
#pragma unroll
      for (int r = 0; r < 4; r++) {
        const int row = m0 + (2 * jj + wm) * 16 + g * 4 + r;
        epilogue_store<EPI>(acc[jj][n][r] + bv, row, col, Nn, res, outf, outb, oq, ok, ov);
      }
    }
}

// ---------------- causal flash attention (paired q-tiles, swapped QK^T) ----------------
// v13 = known-good single-buffered version.
__global__ __launch_bounds__(256) void attn_kernel(
    const unsigned short* __restrict__ q, const unsigned short* __restrict__ k,
    const unsigned short* __restrict__ vt, unsigned short* __restrict__ y) {
  __shared__ unsigned short Ks[64 * 128];   // swizzled [kv][hs]
  __shared__ unsigned short Vs[128 * 64];   // swizzled [d][kv]
  __shared__ unsigned short Ps[4][16 * 64]; // per-wave swizzled [q=i][kv]
  const int tid = threadIdx.x, lane = tid & 63, w = tid >> 6;
  const int i = lane & 15, g = lane >> 4;
  const int p = blockIdx.x, bh = blockIdx.y;
  const int q0A = p * 64, q0B = (31 - p) * 64;
  const int tB = 31 - p;
  const size_t hb = (size_t)bh * (2048 * 128);
  const float sc2 = 0.08838834764831845f * 1.44269504088896341f;

  bf16x8 qfA[4], qfB[4];
  {
    const int qra = q0A + w * 16 + i, qrb = q0B + w * 16 + i;
#pragma unroll
    for (int kc = 0; kc < 4; kc++) {
      qfA[kc] = *(const bf16x8*)(q + hb + (size_t)qra * 128 + kc * 32 + g * 8);
      qfB[kc] = *(const bf16x8*)(q + hb + (size_t)qrb * 128 + kc * 32 + g * 8);
    }
  }
  f32x4 oA[8] = {}, oB[8] = {};
  float mA = -__builtin_inff(), lA = 0.f, mB = -__builtin_inff(), lB = 0.f;

  auto proc = [&](const bf16x8 (&qf)[4], f32x4 (&oacc)[8], float& mrun, float& lrun,
                  bool diag) {
    f32x4 st[4];
#pragma unroll
    for (int ct = 0; ct < 4; ct++) {
      f32x4 a = {};
      const int kvr = ct * 16 + i;
#pragma unroll
      for (int kc = 0; kc < 4; kc++) {
        bf16x8 kf = *(const bf16x8*)((char*)Ks + kvr * 256 + (((kc * 4 + g) ^ (i & 7)) << 4));
        a = mfma16(kf, qf[kc], a);
      }
      st[ct] = a;
    }
    float tm = -__builtin_inff();
    const int ql = w * 16 + i;
#pragma unroll
    for (int ct = 0; ct < 4; ct++)
#pragma unroll
      for (int r = 0; r < 4; r++) {
        float v = st[ct][r] * sc2;
        if (diag) {
          const int kvl = ct * 16 + g * 4 + r;
          if (kvl > ql) v = -__builtin_inff();
        }
        st[ct][r] = v;
        tm = fmaxf(tm, v);
      }
    tm = fmaxf(tm, __shfl_xor(tm, 16, 64));
    tm = fmaxf(tm, __shfl_xor(tm, 32, 64));
    if (!__all(tm - mrun <= 8.f)) {
      const float mnew = fmaxf(mrun, tm);
      const float al = exp2fast(mrun - mnew);
      float ar[4];
#pragma unroll
      for (int r = 0; r < 4; r++) ar[r] = __shfl(al, g * 4 + r, 64);
#pragma unroll
      for (int dt = 0; dt < 8; dt++)
#pragma unroll
        for (int r = 0; r < 4; r++) oacc[dt][r] *= ar[r];
      lrun *= al;
      mrun = mnew;
    }
    float ps = 0.f;
#pragma unroll
    for (int ct = 0; ct < 4; ct++)
#pragma unroll
      for (int r = 0; r < 4; r++) {
        const float pv = exp2fast(st[ct][r] - mrun);
        st[ct][r] = pv;
        ps += pv;
      }
    ps += __shfl_xor(ps, 16, 64);
    ps += __shfl_xor(ps, 32, 64);
    lrun += ps;
#pragma unroll
    for (int ct = 0; ct < 4; ct++) {
      unsigned w0, w1;
      asm("v_cvt_pk_bf16_f32 %0, %1, %2" : "=v"(w0) : "v"(st[ct][0]), "v"(st[ct][1]));
      asm("v_cvt_pk_bf16_f32 %0, %1, %2" : "=v"(w1) : "v"(st[ct][2]), "v"(st[ct][3]));
      char* pb = (char*)&Ps[w][0] + i * 128 +
                 ((((2 * ct + (g >> 1)) ^ (i & 7)) << 4) + (g & 1) * 8);
      *(uint2*)pb = make_uint2(w0, w1);
    }
    bf16x8 pf[2];
#pragma unroll
    for (int kvc = 0; kvc < 2; kvc++)
      pf[kvc] = *(const bf16x8*)((char*)&Ps[w][0] + i * 128 + (((kvc * 4 + g) ^ (i & 7)) << 4));
#pragma unroll
    for (int dt = 0; dt < 8; dt++) {
      const int dr = dt * 16 + i;
#pragma unroll
      for (int kvc = 0; kvc < 2; kvc++) {
        bf16x8 vf = *(const bf16x8*)((char*)Vs + dr * 128 + (((kvc * 4 + g) ^ (dr & 7)) << 4));
        oacc[dt] = mfma16(pf[kvc], vf, oacc[dt]);
      }
    }
  };

  for (int t = 0; t <= tB; ++t) {
    const int j0 = t * 64;
    __syncthreads();
#pragma unroll
    for (int it = 0; it < 4; it++) {
      const int ci = it * 256 + tid;
      const int kv = ci >> 4, ccl = ci & 15;
      gload_lds16(k + hb + (size_t)(j0 + kv) * 128 + ((ccl ^ (kv & 7)) << 3),
                  (char*)Ks + (size_t)(it * 256 + w * 64) * 16);
      const int dd = ci >> 3, c2l = ci & 7;
      gload_lds16(vt + hb + (size_t)dd * 2048 + j0 + ((c2l ^ (dd & 7)) << 3),
                  (char*)Vs + (size_t)(it * 256 + w * 64) * 16);
    }
    __syncthreads();
    if (t <= p) proc(qfA, oA, mA, lA, t == p);
    proc(qfB, oB, mB, lB, t == tB);
  }

  const int bb = bh >> 4, hh = bh & 15;
  auto finish = [&](const f32x4 (&oacc)[8], float lrun, int q0s) {
    const float inv_i = 1.f / lrun;
    float ir[4];
#pragma unroll
    for (int r = 0; r < 4; r++) ir[r] = __shfl(inv_i, g * 4 + r, 64);
#pragma unroll
    for (int r = 0; r < 4; r++) {
      const int row = q0s + w * 16 + g * 4 + r;
#pragma unroll
      for (int dt = 0; dt < 8; dt++) {
        const int d = dt * 16 + i;
        y[((size_t)(bb * 2048 + row)) * 2048 + hh * 128 + d] = f2bf(oacc[dt][r] * ir[r]);
      }
    }
  };
  finish(oA, lA, q0A);
  finish(oB, lB, q0B);
}

// ---------------- launcher ----------------
extern "C" void kernel_launch(void* const* d_in, const int* in_sizes, int n_in,
                              void* d_out, int out_size, void* d_ws, size_t ws_size,
                              hipStream_t stream) {
  const float* x      = (const float*)d_in[0];
  const float* ln1_w  = (const float*)d_in[1];
  const float* ln1_b  = (const float*)d_in[2];
  const float* w_qkv  = (const float*)d_in[3];
  const float* b_qkv  = (const float*)d_in[4];
  const float* w_proj = (const float*)d_in[5];
  const float* b_proj = (const float*)d_in[6];
  const float* ln2_w  = (const float*)d_in[7];
  const float* ln2_b  = (const float*)d_in[8];
  const float* w_fc   = (const float*)d_in[9];
  const float* b_fc   = (const float*)d_in[10];
  const float* w_fc2  = (const float*)d_in[11];
  const float* b_fc2  = (const float*)d_in[12];

  char* ws = (char*)d_ws;
  unsigned short* wt_qkv  = (unsigned short*)(ws + 0);          // 25165824 B
  unsigned short* wt_proj = (unsigned short*)(ws + 25165824);   // 8388608
  unsigned short* qb      = (unsigned short*)(ws + 33554432);   // 16777216
  unsigned short* kb      = (unsigned short*)(ws + 50331648);   // 16777216
  unsigned short* wt_fc   = (unsigned short*)(ws + 67108864);   // 33554432
  unsigned short* wt_fc2  = (unsigned short*)(ws + 100663296);  // 33554432
  unsigned short* hb      = (unsigned short*)(ws + 134217728);  // 16777216 (h1/h2)
  unsigned short* vtb     = (unsigned short*)(ws + 150994944);  // 16777216
  unsigned short* yb      = (unsigned short*)(ws + 167772160);  // 16777216 (vb then y)
  float*          x1      = (float*)(ws + 184549376);           // 33554432 (ends 218103808)
  unsigned short* hfc     = (unsigned short*)(ws + 0);          // 67108864, aliases dead wt_qkv/wt_proj/qb/kb
  float* outp = (float*)d_out;

  transpose_to_bf16<<<dim3(6144 / 64, 2048 / 64), 256, 0, stream>>>(w_qkv, wt_qkv, 2048, 6144);
  transpose_to_bf16<<<dim3(2048 / 64, 2048 / 64), 256, 0, stream>>>(w_proj, wt_proj, 2048, 2048);
  transpose_to_bf16<<<dim3(8192 / 64, 2048 / 64), 256, 0, stream>>>(w_fc, wt_fc, 2048, 8192);
  transpose_to_bf16<<<dim3(2048 / 64, 8192 / 64), 256, 0, stream>>>(w_fc2, wt_fc2, 8192, 2048);

  ln_kernel<<<4096, 256, 0, stream>>>(x, ln1_w, ln1_b, hb);

  // qkv: 128x256 tiles -> 32x24 = 768 blocks (3 clean rounds)
  gemm128<0><<<768, 512, 0, stream>>>(
      hb, wt_qkv, b_qkv, nullptr, nullptr, nullptr, qb, kb, yb, 6144, 2048, 24);
  dim3 tb(32, 8);
  transpose_v<<<dim3(2048 / 32, 128 / 32, 32), tb, 0, stream>>>(yb, vtb);

  // paired causal q-tiles: 16 pairs x 32 bh = 512 blocks, uniform work
  attn_kernel<<<dim3(16, 32), 256, 0, stream>>>(qb, kb, vtb, yb);

  // proj + residual -> x1 (f32): 32x8 = 256 blocks (1 clean round)
  gemm128<2><<<256, 512, 0, stream>>>(
      yb, wt_proj, b_proj, x, x1, nullptr, nullptr, nullptr, nullptr, 2048, 2048, 8);

  ln_kernel<<<4096, 256, 0, stream>>>(x1, ln2_w, ln2_b, hb);

  // fc + GELU -> hfc (bf16): 256x256 tiles, 512 blocks (2 clean rounds)
  gemm256<1><<<512, 512, 0, stream>>>(
      hb, wt_fc, b_fc, nullptr, nullptr, hfc, nullptr, nullptr, nullptr, 8192, 2048, 32);

  // fc2 + residual -> out (f32): 32x8 = 256 blocks (1 clean round)
  gemm128<2><<<256, 512, 0, stream>>>(
      hfc, wt_fc2, b_fc2, x1, outp, nullptr, nullptr, nullptr, nullptr, 2048, 8192, 8);
}